// Round 6
// baseline (781.833 us; speedup 1.0000x reference)
//
#include <hip/hip_runtime.h>

typedef unsigned int u32;
typedef unsigned short u16;
typedef _Float16 h2 __attribute__((ext_vector_type(2)));
typedef _Float16 h4 __attribute__((ext_vector_type(4)));
typedef float f4 __attribute__((ext_vector_type(4)));

#define B_ 64
#define N_ 8192
#define DI 8
#define O_ 10
#define DO_ 16
#define OD 160          // O_*DO_
#define NB 256          // fused grid: 1 block/CU, all co-resident (LDS-forced)
#define NCH 32          // n per block (fused): 256*32 = 8192
#define WROW (OD * DI)  // 1280 elems per n
#define WLN (NCH * WROW)// 40960 f16 = 81920 B
#define XROW 264        // padded x row per b (f16): 32n*8 + 8 pad -> bank stride 4
#define CSTR 164        // combine row stride (floats), proven R13

// ---- fallback (R16 proven) params ----
#define NCHUNK 8
#define CHN 2
#define NCHK (NCHUNK / CHN)
#define CHH (CHN * WROW)

// cvt_pkrtz returns __fp16-vec2; bit_cast to our _Float16-vec2 (same bits).
static __device__ __forceinline__ h2 pkrtz(float a, float b) {
    return __builtin_bit_cast(h2, __builtin_amdgcn_cvt_pkrtz(a, b));
}

// Packed-f16 sum across the four 16-lane rows, replicated to all lanes --
// PROVEN R13 chain (ds_swizzle xor^16 + ds_bpermute xor^32). permlane swaps
// are NOT equivalent (R14/R15 evidence); do not substitute.
static __device__ __forceinline__ h2 hsum4(h2 v, int a32) {
    int pi = __builtin_bit_cast(int, v);
    h2 pk = v + __builtin_bit_cast(h2, __builtin_amdgcn_ds_swizzle(pi, 0x401F));
    pi = __builtin_bit_cast(int, pk);
    pk = pk + __builtin_bit_cast(h2, __builtin_amdgcn_ds_bpermute(a32, pi));
    return pk;
}

// Device-scope grid barrier: monotonic counter (memset to 0 per launch).
// threadfence BEFORE arrive = release (P/Vb pushed to coherence point);
// threadfence AFTER wait = acquire (invalidates L1 -- P/Vb addresses repeat
// across rounds, stale-L1 re-reads would be silent corruption).
static __device__ __forceinline__ void gbar(u32* bar, u32 target) {
    __threadfence();
    __syncthreads();
    if (threadIdx.x == 0) {
        __hip_atomic_fetch_add(bar, 1u, __ATOMIC_ACQ_REL, __HIP_MEMORY_SCOPE_AGENT);
        u32 v = __hip_atomic_load(bar, __ATOMIC_ACQUIRE, __HIP_MEMORY_SCOPE_AGENT);
        while (v < target) {
            __builtin_amdgcn_s_sleep(16);
            v = __hip_atomic_load(bar, __ATOMIC_ACQUIRE, __HIP_MEMORY_SCOPE_AGENT);
        }
    }
    __syncthreads();
    __threadfence();
}

// R17: persistent fused kernel. W (80 KB) + x (33 KB) staged to LDS as f16
// ONCE; all 3 routing iterations run out of LDS (W fetched from HBM 1x not
// 3x -- R16's counters showed 99 MB fetch x3 passes). Cross-block reduce via
// fp16 partials (proven R13 scheme, 256 parts) + 5 global barriers. Blocks
// 0..63 reduce+squash batch b=blockIdx in-kernel (proven reduce_fin logic).
// MFMA mapping unchanged (f32_16x16x16f16, K=8 of 16 zero-padded).
__global__ __launch_bounds__(512, 2)
void caps_fused(const float* __restrict__ Xf, const float* __restrict__ Wf,
                u32* bar, float* __restrict__ V0f, u16* __restrict__ Vb,
                _Float16* __restrict__ P, float* __restrict__ out) {
    __shared__ _Float16 wl[WLN];            // 81920 B
    __shared__ _Float16 xl[B_ * XROW];      // 33792 B
    __shared__ float cmb[B_ * CSTR];        // 41984 B (combine + reduce scratch)

    const int tid  = threadIdx.x;
    const int lane = tid & 63;
    const int c    = lane & 15;
    const int hh   = lane >> 4;
    const int w    = __builtin_amdgcn_readfirstlane(tid >> 6);
    const int tau  = w & 3, eta = w >> 2;
    const int b    = tau * 16 + c;
    const int bid  = blockIdx.x;
    const int nb   = bid * NCH;
    const int a32  = (lane ^ 32) << 2;
    const int ioff = (hh < 2) ? 4 * hh : 0;

    // ---- stage W + x (issue all loads first, then convert+write) ----
    {
        const float* src = Wf + (size_t)nb * WROW;
        float4 wv[20];
        #pragma unroll
        for (int k = 0; k < 20; ++k) wv[k] = *(const float4*)(src + (tid + k * 512) * 4);
        const float* xs = Xf + ((size_t)(tid >> 3) * N_ + nb) * DI;
        float4 xv[8];
        #pragma unroll
        for (int k = 0; k < 8; ++k) xv[k] = *(const float4*)(xs + ((tid & 7) + k * 8) * 4);
        #pragma unroll
        for (int k = 0; k < 20; ++k) {
            h2 lo = pkrtz(wv[k].x, wv[k].y), hi = pkrtz(wv[k].z, wv[k].w);
            h4 hv; hv[0] = lo[0]; hv[1] = lo[1]; hv[2] = hi[0]; hv[3] = hi[1];
            *(h4*)&wl[(tid + k * 512) * 4] = hv;
        }
        #pragma unroll
        for (int k = 0; k < 8; ++k) {
            const int pos = ((tid & 7) + k * 8) * 4;   // f32 idx in 256-el row
            h2 lo = pkrtz(xv[k].x, xv[k].y), hi = pkrtz(xv[k].z, xv[k].w);
            h4 hv; hv[0] = lo[0]; hv[1] = lo[1]; hv[2] = hi[0]; hv[3] = hi[1];
            *(h4*)&xl[(tid >> 3) * XROW + pos] = hv;
        }
    }
    __syncthreads();

    const f4 fz = {0.f, 0.f, 0.f, 0.f};
    f4 acc[O_], vv[O_];
    const _Float16* xrow = xl + b * XROW + ioff;

    auto loadvv = [&]() {
        const _Float16* vp = (const _Float16*)Vb + (size_t)b * OD + 4 * hh;
        #pragma unroll
        for (int oo = 0; oo < O_; ++oo) {
            const h4 hv = *(const h4*)(vp + oo * DO_);
            vv[oo][0] = (float)hv[0]; vv[oo][1] = (float)hv[1];
            vv[oo][2] = (float)hv[2]; vv[oo][3] = (float)hv[3];
        }
    };

    // one routing n-step with softmax (proven R16 math, inputs from LDS)
    auto step1 = [&](int sn) {
        h4 bf = {(_Float16)0.f, (_Float16)0.f, (_Float16)0.f, (_Float16)0.f};
        if (hh < 2) bf = *(const h4*)(xrow + sn * 8);
        const _Float16* wr = wl + sn * WROW + c * DI + ioff;
        f4 u[O_];
        #pragma unroll
        for (int oo = 0; oo < O_; ++oo) {
            h4 af = {(_Float16)0.f, (_Float16)0.f, (_Float16)0.f, (_Float16)0.f};
            if (hh < 2) af = *(const h4*)(wr + oo * (DO_ * DI));
            u[oo] = __builtin_amdgcn_mfma_f32_16x16x16f16(af, bf, fz, 0, 0, 0);
        }
        float tex[O_];
        #pragma unroll
        for (int q = 0; q < 5; ++q) {
            const int o0 = 2 * q, o1 = 2 * q + 1;
            const float p0 = u[o0][0]*vv[o0][0] + u[o0][1]*vv[o0][1]
                           + u[o0][2]*vv[o0][2] + u[o0][3]*vv[o0][3];
            const float p1 = u[o1][0]*vv[o1][0] + u[o1][1]*vv[o1][1]
                           + u[o1][2]*vv[o1][2] + u[o1][3]*vv[o1][3];
            const h2 pk = hsum4(pkrtz(p0, p1), a32);
            tex[o0] = __expf((float)pk[0]);
            tex[o1] = __expf((float)pk[1]);
        }
        const float den = (((tex[0] + tex[1]) + (tex[2] + tex[3]))
                         + ((tex[4] + tex[5]) + (tex[6] + tex[7])))
                         + (tex[8] + tex[9]);
        const float rinv = 1.0f / den;
        #pragma unroll
        for (int oo = 0; oo < O_; ++oo) {
            const float co = tex[oo] * rinv;
            acc[oo][0] = fmaf(co, u[oo][0], acc[oo][0]);
            acc[oo][1] = fmaf(co, u[oo][1], acc[oo][1]);
            acc[oo][2] = fmaf(co, u[oo][2], acc[oo][2]);
            acc[oo][3] = fmaf(co, u[oo][3], acc[oo][3]);
        }
    };

    // eta-combine in LDS + per-block fp16 partial write (proven R13 scheme)
    auto epi = [&](float sc) {
        if (eta == 1) {
            #pragma unroll
            for (int oo = 0; oo < O_; ++oo)
                *(f4*)&cmb[b * CSTR + oo * DO_ + 4 * hh] = acc[oo];
        }
        __syncthreads();
        if (eta == 0) {
            _Float16* my = P + (size_t)bid * (B_ * OD) + (size_t)b * OD;
            #pragma unroll
            for (int oo = 0; oo < O_; ++oo) {
                const f4 t = acc[oo] + *(const f4*)&cmb[b * CSTR + oo * DO_ + 4 * hh];
                h4 hq;
                hq[0] = (_Float16)(sc * t[0]); hq[1] = (_Float16)(sc * t[1]);
                hq[2] = (_Float16)(sc * t[2]); hq[3] = (_Float16)(sc * t[3]);
                *(h4*)(my + oo * DO_ + 4 * hh) = hq;
            }
        }
    };

    // in-kernel cross-block reduce + squash for batch b0 = bid (blocks 0..63)
    auto reduceF = [&](int r) {
        float* sg = cmb;            // 480 f32
        float* ss = cmb + 512;      // 160 f32
        float* sca = cmb + 704;     // 16 f32
        if (tid < 480) {
            const int g = tid / 160, od = tid - g * 160;
            float a2 = 0.0f;
            const _Float16* p0 = P + (size_t)bid * OD + od;
            for (int p = g; p < NB; p += 3)
                a2 += (float)p0[(size_t)p * (B_ * OD)];
            sg[g * 160 + od] = a2;
        }
        __syncthreads();
        if (tid < 160) ss[tid] = sg[tid] + sg[160 + tid] + sg[320 + tid];
        __syncthreads();
        if (tid < 16) {
            float nrm = 0.0f;
            #pragma unroll
            for (int o = 0; o < O_; ++o) { const float x = ss[o * DO_ + tid]; nrm = fmaf(x, x, nrm); }
            sca[tid] = nrm / (1.0f + nrm) * rsqrtf(nrm + 1e-9f);
        }
        __syncthreads();
        if (tid < 160) {
            const float v = ss[tid] * sca[tid & 15];
            const int idx = bid * OD + tid;
            if (r == 0) {
                V0f[idx] = v;
                _Float16 hcv = (_Float16)v;
                Vb[idx] = __builtin_bit_cast(u16, hcv);
            } else if (r == 1) {
                _Float16 hcv = (_Float16)(V0f[idx] + v);
                Vb[idx] = __builtin_bit_cast(u16, hcv);
            } else {
                out[idx] = v;
            }
        }
        __syncthreads();
    };

    // ---- round 0: uniform c = 0.1, chain through MFMA C ----
    #pragma unroll
    for (int oo = 0; oo < O_; ++oo) acc[oo] = fz;
    #pragma unroll 1
    for (int st = 0; st < 16; ++st) {
        const int sn = eta * 16 + st;
        h4 bf = {(_Float16)0.f, (_Float16)0.f, (_Float16)0.f, (_Float16)0.f};
        if (hh < 2) bf = *(const h4*)(xrow + sn * 8);
        const _Float16* wr = wl + sn * WROW + c * DI + ioff;
        #pragma unroll
        for (int oo = 0; oo < O_; ++oo) {
            h4 af = {(_Float16)0.f, (_Float16)0.f, (_Float16)0.f, (_Float16)0.f};
            if (hh < 2) af = *(const h4*)(wr + oo * (DO_ * DI));
            acc[oo] = __builtin_amdgcn_mfma_f32_16x16x16f16(af, bf, acc[oo], 0, 0, 0);
        }
    }
    epi(0.1f);
    gbar(bar, NB);
    if (bid < B_) reduceF(0);
    gbar(bar, 2 * NB);
    loadvv();

    // ---- round 1 ----
    #pragma unroll
    for (int oo = 0; oo < O_; ++oo) acc[oo] = fz;
    #pragma unroll 1
    for (int st = 0; st < 16; ++st) step1(eta * 16 + st);
    epi(1.0f);
    gbar(bar, 3 * NB);
    if (bid < B_) reduceF(1);
    gbar(bar, 4 * NB);
    loadvv();

    // ---- round 2 ----
    #pragma unroll
    for (int oo = 0; oo < O_; ++oo) acc[oo] = fz;
    #pragma unroll 1
    for (int st = 0; st < 16; ++st) step1(eta * 16 + st);
    epi(1.0f);

    // final barrier: everyone arrives; only reducer blocks wait and finish
    __threadfence();
    __syncthreads();
    if (tid == 0)
        __hip_atomic_fetch_add(bar, 1u, __ATOMIC_ACQ_REL, __HIP_MEMORY_SCOPE_AGENT);
    if (bid < B_) {
        if (tid == 0) {
            u32 v = __hip_atomic_load(bar, __ATOMIC_ACQUIRE, __HIP_MEMORY_SCOPE_AGENT);
            while (v < 5 * NB) {
                __builtin_amdgcn_s_sleep(16);
                v = __hip_atomic_load(bar, __ATOMIC_ACQUIRE, __HIP_MEMORY_SCOPE_AGENT);
            }
        }
        __syncthreads();
        __threadfence();
        reduceF(2);
    }
}

// ================= fallback path (R16 proven, atomic accumulator) =========
template <int PHASE, int TAIL>
__global__ __launch_bounds__(256, 3)
void caps_pass(const float* __restrict__ Xf, const float* __restrict__ Wf,
               const u16* __restrict__ Vb, float* __restrict__ Sout,
               _Float16* __restrict__ Sh) {
    __shared__ _Float16 stage[2 * CHH];

    const int tid  = threadIdx.x;
    const int lane = tid & 63;
    const int c    = lane & 15;
    const int hh   = lane >> 4;
    const int tau  = __builtin_amdgcn_readfirstlane(tid >> 6);
    const int b    = tau * 16 + c;
    const int nb   = blockIdx.x * NCHUNK;
    const int a32  = (lane ^ 32) << 2;

    int off[5];
    #pragma unroll
    for (int k = 0; k < 5; ++k) off[k] = (tid + k * 256) * 2;

    float2 st[5];
    {
        const float* src = Wf + (size_t)nb * WROW;
        #pragma unroll
        for (int k = 0; k < 5; ++k) st[k] = *(const float2*)(src + off[k]);
        #pragma unroll
        for (int k = 0; k < 5; ++k)
            *(h2*)&stage[off[k]] = pkrtz(st[k].x, st[k].y);
    }

    f4 vv[O_];
    if (PHASE > 0) {
        const _Float16* vp = (const _Float16*)Vb + (size_t)b * OD + 4 * hh;
        #pragma unroll
        for (int oo = 0; oo < O_; ++oo) {
            const h4 hv = *(const h4*)(vp + oo * DO_);
            vv[oo][0] = (float)hv[0]; vv[oo][1] = (float)hv[1];
            vv[oo][2] = (float)hv[2]; vv[oo][3] = (float)hv[3];
        }
    }

    const f4 fz = {0.f, 0.f, 0.f, 0.f};
    f4 acc[O_];
    #pragma unroll
    for (int oo = 0; oo < O_; ++oo) acc[oo] = fz;

    const int ioff = (hh < 2) ? 4 * hh : 0;
    const float* xb = Xf + ((size_t)b * N_ + nb) * DI + ioff;
    float4 xcur = *(const float4*)xb;

    __syncthreads();

    #pragma unroll 1
    for (int ch = 0; ch < NCHK; ++ch) {
        if (ch < NCHK - 1) {
            const float* src = Wf + (size_t)(nb + (ch + 1) * CHN) * WROW;
            #pragma unroll
            for (int k = 0; k < 5; ++k) st[k] = *(const float2*)(src + off[k]);
        }
        const _Float16* wb = stage + (ch & 1) * CHH;

        #pragma unroll
        for (int kk = 0; kk < CHN; ++kk) {
            const int s = ch * CHN + kk;
            float4 xnext = xcur;
            if (s < NCHUNK - 1)
                xnext = *(const float4*)(xb + (size_t)(s + 1) * DI);

            h4 bf = {(_Float16)0.f, (_Float16)0.f, (_Float16)0.f, (_Float16)0.f};
            if (hh < 2) {
                const h2 lo = pkrtz(xcur.x, xcur.y);
                const h2 hi = pkrtz(xcur.z, xcur.w);
                bf[0] = lo[0]; bf[1] = lo[1]; bf[2] = hi[0]; bf[3] = hi[1];
            }
            xcur = xnext;

            const _Float16* wr = wb + kk * WROW + c * DI + ioff;
            f4 u[O_];
            #pragma unroll
            for (int oo = 0; oo < O_; ++oo) {
                h4 af = {(_Float16)0.f, (_Float16)0.f, (_Float16)0.f, (_Float16)0.f};
                if (hh < 2) af = *(const h4*)(wr + oo * (DO_ * DI));
                if (PHASE == 0) {
                    acc[oo] = __builtin_amdgcn_mfma_f32_16x16x16f16(af, bf, acc[oo], 0, 0, 0);
                } else {
                    u[oo] = __builtin_amdgcn_mfma_f32_16x16x16f16(af, bf, fz, 0, 0, 0);
                }
            }

            if (PHASE > 0) {
                float tex[O_];
                #pragma unroll
                for (int q = 0; q < 5; ++q) {
                    const int o0 = 2 * q, o1 = 2 * q + 1;
                    const float p0 = u[o0][0]*vv[o0][0] + u[o0][1]*vv[o0][1]
                                   + u[o0][2]*vv[o0][2] + u[o0][3]*vv[o0][3];
                    const float p1 = u[o1][0]*vv[o1][0] + u[o1][1]*vv[o1][1]
                                   + u[o1][2]*vv[o1][2] + u[o1][3]*vv[o1][3];
                    const h2 pk = hsum4(pkrtz(p0, p1), a32);
                    tex[o0] = __expf((float)pk[0]);
                    tex[o1] = __expf((float)pk[1]);
                }
                const float den = (((tex[0] + tex[1]) + (tex[2] + tex[3]))
                                 + ((tex[4] + tex[5]) + (tex[6] + tex[7])))
                                 + (tex[8] + tex[9]);
                const float rinv = 1.0f / den;
                #pragma unroll
                for (int oo = 0; oo < O_; ++oo) {
                    const float co = tex[oo] * rinv;
                    acc[oo][0] = fmaf(co, u[oo][0], acc[oo][0]);
                    acc[oo][1] = fmaf(co, u[oo][1], acc[oo][1]);
                    acc[oo][2] = fmaf(co, u[oo][2], acc[oo][2]);
                    acc[oo][3] = fmaf(co, u[oo][3], acc[oo][3]);
                }
            }
        }

        if (ch < NCHK - 1) {
            _Float16* dst = stage + ((ch + 1) & 1) * CHH;
            #pragma unroll
            for (int k = 0; k < 5; ++k)
                *(h2*)&dst[off[k]] = pkrtz(st[k].x, st[k].y);
        }
        __syncthreads();
    }

    const float sc = (PHASE == 0) ? 0.1f : 1.0f;
    {
        float* Sg = Sout + (size_t)b * OD;
        #pragma unroll
        for (int oo = 0; oo < O_; ++oo) {
            atomicAdd(&Sg[oo * DO_ + 4 * hh + 0], sc * acc[oo][0]);
            atomicAdd(&Sg[oo * DO_ + 4 * hh + 1], sc * acc[oo][1]);
            atomicAdd(&Sg[oo * DO_ + 4 * hh + 2], sc * acc[oo][2]);
            atomicAdd(&Sg[oo * DO_ + 4 * hh + 3], sc * acc[oo][3]);
        }
    }
    (void)Sh;
}

template <int PHASE>
__global__ __launch_bounds__(1024)
void caps_finalize(float* __restrict__ S, float* __restrict__ V0f,
                   u16* __restrict__ Vb, float* __restrict__ out) {
    const int tid = threadIdx.x;
    const int b = tid >> 4, d = tid & 15;
    float sv[O_];
    float norm = 0.0f;
    #pragma unroll
    for (int o = 0; o < O_; ++o) {
        sv[o] = S[b * OD + o * DO_ + d];
        norm = fmaf(sv[o], sv[o], norm);
    }
    const float scale = norm / (1.0f + norm) * rsqrtf(norm + 1e-9f);
    #pragma unroll
    for (int o = 0; o < O_; ++o) {
        const int idx = b * OD + o * DO_ + d;
        const float v = scale * sv[o];
        if (PHASE == 0) {
            V0f[idx] = v;
            _Float16 hcv = (_Float16)v;
            Vb[idx] = __builtin_bit_cast(u16, hcv);
            S[idx] = 0.0f;
        } else if (PHASE == 1) {
            _Float16 hcv = (_Float16)(V0f[idx] + v);
            Vb[idx] = __builtin_bit_cast(u16, hcv);
            S[idx] = 0.0f;
        } else {
            out[idx] = v;
        }
    }
}

extern "C" void kernel_launch(void* const* d_in, const int* in_sizes, int n_in,
                              void* d_out, int out_size, void* d_ws, size_t ws_size,
                              hipStream_t stream) {
    const float* Xf = (const float*)d_in[0];   // x: [64, 8192, 8] fp32
    const float* Wf = (const float*)d_in[1];   // W: [1, 8192, 10, 16, 8] fp32
    float* out = (float*)d_out;

    const size_t velems = (size_t)B_ * OD;                 // 10240
    float* V0f = (float*)d_ws;                             // 40960 B
    u16* Vb = (u16*)(V0f + velems);                        // 20480 B -> ends 61440
    u32* bar = (u32*)((char*)d_ws + 61440);                // 64 B counter
    const size_t pbase = 61504;
    const size_t need = pbase + (size_t)NB * velems * 2;   // ~5.3 MB

    if (ws_size >= need) {
        _Float16* P = (_Float16*)((char*)d_ws + pbase);
        (void)hipMemsetAsync(bar, 0, 64, stream);
        caps_fused<<<dim3(NB), dim3(512), 0, stream>>>(Xf, Wf, bar, V0f, Vb, P, out);
    } else {
        // fallback: global atomic accumulator (R16 proven path)
        float* S = (float*)((char*)d_ws + pbase);
        const dim3 grid(N_ / NCHUNK), blk(256), one(1), fblk(1024);
        (void)hipMemsetAsync(S, 0, velems * sizeof(float), stream);
        caps_pass<0, 2><<<grid, blk, 0, stream>>>(Xf, Wf, nullptr, S, nullptr);
        caps_finalize<0><<<one, fblk, 0, stream>>>(S, V0f, Vb, nullptr);
        caps_pass<1, 2><<<grid, blk, 0, stream>>>(Xf, Wf, Vb, S, nullptr);
        caps_finalize<1><<<one, fblk, 0, stream>>>(S, V0f, Vb, nullptr);
        caps_pass<1, 2><<<grid, blk, 0, stream>>>(Xf, Wf, Vb, S, nullptr);
        caps_finalize<2><<<one, fblk, 0, stream>>>(S, nullptr, nullptr, out);
    }
}

// Round 7
// 535.031 us; speedup vs baseline: 1.4613x; 1.4613x over previous
//
#include <hip/hip_runtime.h>

typedef unsigned int u32;
typedef unsigned short u16;
typedef _Float16 h2 __attribute__((ext_vector_type(2)));
typedef _Float16 h4 __attribute__((ext_vector_type(4)));
typedef float f4 __attribute__((ext_vector_type(4)));

#define B_ 64
#define N_ 8192
#define DI 8
#define O_ 10
#define DO_ 16
#define OD 160          // O_*DO_
#define NB 256          // fused grid: 1 block/CU, all co-resident (LDS-forced)
#define NCH 32          // n per block (fused): 256*32 = 8192
#define WROW (OD * DI)  // 1280 elems per n
#define WLN (NCH * WROW)// 40960 f16 = 81920 B
#define XROW 264        // padded x row per b (f16)
#define CSTR 164        // combine row stride (floats), proven R13

// ---- fallback (R16 proven) params ----
#define NCHUNK 8
#define CHN 2
#define NCHK (NCHUNK / CHN)
#define CHH (CHN * WROW)

// cvt_pkrtz returns __fp16-vec2; bit_cast to our _Float16-vec2 (same bits).
static __device__ __forceinline__ h2 pkrtz(float a, float b) {
    return __builtin_bit_cast(h2, __builtin_amdgcn_cvt_pkrtz(a, b));
}

// Packed-f16 sum across the four 16-lane rows, replicated to all lanes --
// PROVEN R13 chain (ds_swizzle xor^16 + ds_bpermute xor^32). permlane swaps
// are NOT equivalent (R14/R15 evidence); do not substitute.
static __device__ __forceinline__ h2 hsum4(h2 v, int a32) {
    int pi = __builtin_bit_cast(int, v);
    h2 pk = v + __builtin_bit_cast(h2, __builtin_amdgcn_ds_swizzle(pi, 0x401F));
    pi = __builtin_bit_cast(int, pk);
    pk = pk + __builtin_bit_cast(h2, __builtin_amdgcn_ds_bpermute(a32, pi));
    return pk;
}

// R18 barrier: R17's single-line counter+acquire-poll barrier serialized the
// whole kernel (732us at 3% busy: 256 spinning acquire-loads ping-pong the
// RMW line across 8 XCD L2s and invalidate caches every poll). Split design:
//   cnt line  : receives exactly NB fetch_adds per barrier, nobody polls it.
//   flag line : written ONCE by the last arriver, polled with RELAXED loads.
static __device__ __forceinline__ void gbar_arrive(u32* cnt, u32* flag, u32 k) {
    __threadfence();
    __syncthreads();
    if (threadIdx.x == 0) {
        const u32 old = __hip_atomic_fetch_add(cnt, 1u, __ATOMIC_ACQ_REL,
                                               __HIP_MEMORY_SCOPE_AGENT);
        if (old == k * NB - 1)
            __hip_atomic_store(flag, k, __ATOMIC_RELEASE, __HIP_MEMORY_SCOPE_AGENT);
    }
}
static __device__ __forceinline__ void gbar_wait(u32* flag, u32 k) {
    if (threadIdx.x == 0) {
        while (__hip_atomic_load(flag, __ATOMIC_RELAXED, __HIP_MEMORY_SCOPE_AGENT) < k)
            __builtin_amdgcn_s_sleep(32);
    }
    __syncthreads();
    __threadfence();   // acquire: invalidate stale L1/L2 before re-reading P/Vb
}

// R18 = R17 fused persistent kernel (traffic proven: 54 MB total vs 585 MB
// for 3 passes) + cheap barriers + pipelined reduce. W (80 KB) + x (33 KB)
// staged to LDS as f16 once; 3 routing rounds from LDS; cross-block reduce
// via fp16 partials; blocks 0..63 reduce+squash in-kernel.
__global__ __launch_bounds__(512, 2)
void caps_fused(const float* __restrict__ Xf, const float* __restrict__ Wf,
                u32* bar, float* __restrict__ V0f, u16* __restrict__ Vb,
                _Float16* __restrict__ P, float* __restrict__ out) {
    __shared__ _Float16 wl[WLN];            // 81920 B
    __shared__ _Float16 xl[B_ * XROW];      // 33792 B
    __shared__ float cmb[B_ * CSTR];        // 41984 B (combine + reduce scratch)

    const int tid  = threadIdx.x;
    const int lane = tid & 63;
    const int c    = lane & 15;
    const int hh   = lane >> 4;
    const int w    = __builtin_amdgcn_readfirstlane(tid >> 6);
    const int tau  = w & 3, eta = w >> 2;
    const int b    = tau * 16 + c;
    const int bid  = blockIdx.x;
    const int nb   = bid * NCH;
    const int a32  = (lane ^ 32) << 2;
    const int ioff = (hh < 2) ? 4 * hh : 0;

    u32* cnt  = bar;
    u32* flag = bar + 32;    // separate 128-B cache line

    // ---- stage W + x (issue all loads first, then convert+write) ----
    {
        const float* src = Wf + (size_t)nb * WROW;
        float4 wv[20];
        #pragma unroll
        for (int k = 0; k < 20; ++k) wv[k] = *(const float4*)(src + (tid + k * 512) * 4);
        const float* xs = Xf + ((size_t)(tid >> 3) * N_ + nb) * DI;
        float4 xv[8];
        #pragma unroll
        for (int k = 0; k < 8; ++k) xv[k] = *(const float4*)(xs + ((tid & 7) + k * 8) * 4);
        #pragma unroll
        for (int k = 0; k < 20; ++k) {
            h2 lo = pkrtz(wv[k].x, wv[k].y), hi = pkrtz(wv[k].z, wv[k].w);
            h4 hv; hv[0] = lo[0]; hv[1] = lo[1]; hv[2] = hi[0]; hv[3] = hi[1];
            *(h4*)&wl[(tid + k * 512) * 4] = hv;
        }
        #pragma unroll
        for (int k = 0; k < 8; ++k) {
            const int pos = ((tid & 7) + k * 8) * 4;
            h2 lo = pkrtz(xv[k].x, xv[k].y), hi = pkrtz(xv[k].z, xv[k].w);
            h4 hv; hv[0] = lo[0]; hv[1] = lo[1]; hv[2] = hi[0]; hv[3] = hi[1];
            *(h4*)&xl[(tid >> 3) * XROW + pos] = hv;
        }
    }
    __syncthreads();

    const f4 fz = {0.f, 0.f, 0.f, 0.f};
    f4 acc[O_], vv[O_];
    const _Float16* xrow = xl + b * XROW + ioff;

    auto loadvv = [&]() {
        const _Float16* vp = (const _Float16*)Vb + (size_t)b * OD + 4 * hh;
        #pragma unroll
        for (int oo = 0; oo < O_; ++oo) {
            const h4 hv = *(const h4*)(vp + oo * DO_);
            vv[oo][0] = (float)hv[0]; vv[oo][1] = (float)hv[1];
            vv[oo][2] = (float)hv[2]; vv[oo][3] = (float)hv[3];
        }
    };

    auto step1 = [&](int sn) {
        h4 bf = {(_Float16)0.f, (_Float16)0.f, (_Float16)0.f, (_Float16)0.f};
        if (hh < 2) bf = *(const h4*)(xrow + sn * 8);
        const _Float16* wr = wl + sn * WROW + c * DI + ioff;
        f4 u[O_];
        #pragma unroll
        for (int oo = 0; oo < O_; ++oo) {
            h4 af = {(_Float16)0.f, (_Float16)0.f, (_Float16)0.f, (_Float16)0.f};
            if (hh < 2) af = *(const h4*)(wr + oo * (DO_ * DI));
            u[oo] = __builtin_amdgcn_mfma_f32_16x16x16f16(af, bf, fz, 0, 0, 0);
        }
        float tex[O_];
        #pragma unroll
        for (int q = 0; q < 5; ++q) {
            const int o0 = 2 * q, o1 = 2 * q + 1;
            const float p0 = u[o0][0]*vv[o0][0] + u[o0][1]*vv[o0][1]
                           + u[o0][2]*vv[o0][2] + u[o0][3]*vv[o0][3];
            const float p1 = u[o1][0]*vv[o1][0] + u[o1][1]*vv[o1][1]
                           + u[o1][2]*vv[o1][2] + u[o1][3]*vv[o1][3];
            const h2 pk = hsum4(pkrtz(p0, p1), a32);
            tex[o0] = __expf((float)pk[0]);
            tex[o1] = __expf((float)pk[1]);
        }
        const float den = (((tex[0] + tex[1]) + (tex[2] + tex[3]))
                         + ((tex[4] + tex[5]) + (tex[6] + tex[7])))
                         + (tex[8] + tex[9]);
        const float rinv = 1.0f / den;
        #pragma unroll
        for (int oo = 0; oo < O_; ++oo) {
            const float co = tex[oo] * rinv;
            acc[oo][0] = fmaf(co, u[oo][0], acc[oo][0]);
            acc[oo][1] = fmaf(co, u[oo][1], acc[oo][1]);
            acc[oo][2] = fmaf(co, u[oo][2], acc[oo][2]);
            acc[oo][3] = fmaf(co, u[oo][3], acc[oo][3]);
        }
    };

    auto epi = [&](float sc) {
        if (eta == 1) {
            #pragma unroll
            for (int oo = 0; oo < O_; ++oo)
                *(f4*)&cmb[b * CSTR + oo * DO_ + 4 * hh] = acc[oo];
        }
        __syncthreads();
        if (eta == 0) {
            _Float16* my = P + (size_t)bid * (B_ * OD) + (size_t)b * OD;
            #pragma unroll
            for (int oo = 0; oo < O_; ++oo) {
                const f4 t = acc[oo] + *(const f4*)&cmb[b * CSTR + oo * DO_ + 4 * hh];
                h4 hq;
                hq[0] = (_Float16)(sc * t[0]); hq[1] = (_Float16)(sc * t[1]);
                hq[2] = (_Float16)(sc * t[2]); hq[3] = (_Float16)(sc * t[3]);
                *(h4*)(my + oo * DO_ + 4 * hh) = hq;
            }
        }
    };

    auto reduceF = [&](int r) {
        float* sg = cmb;
        float* ss = cmb + 512;
        float* sca = cmb + 704;
        if (tid < 480) {
            const int g = tid / 160, od = tid - g * 160;
            float a2 = 0.0f;
            const _Float16* p0 = P + (size_t)bid * OD + od;
            #pragma unroll 8
            for (int p = g; p < NB; p += 3)
                a2 += (float)p0[(size_t)p * (B_ * OD)];
            sg[g * 160 + od] = a2;
        }
        __syncthreads();
        if (tid < 160) ss[tid] = sg[tid] + sg[160 + tid] + sg[320 + tid];
        __syncthreads();
        if (tid < 16) {
            float nrm = 0.0f;
            #pragma unroll
            for (int o = 0; o < O_; ++o) { const float x = ss[o * DO_ + tid]; nrm = fmaf(x, x, nrm); }
            sca[tid] = nrm / (1.0f + nrm) * rsqrtf(nrm + 1e-9f);
        }
        __syncthreads();
        if (tid < 160) {
            const float v = ss[tid] * sca[tid & 15];
            const int idx = bid * OD + tid;
            if (r == 0) {
                V0f[idx] = v;
                _Float16 hcv = (_Float16)v;
                Vb[idx] = __builtin_bit_cast(u16, hcv);
            } else if (r == 1) {
                _Float16 hcv = (_Float16)(V0f[idx] + v);
                Vb[idx] = __builtin_bit_cast(u16, hcv);
            } else {
                out[idx] = v;
            }
        }
        __syncthreads();
    };

    // ---- round 0: uniform c = 0.1, chain through MFMA C ----
    #pragma unroll
    for (int oo = 0; oo < O_; ++oo) acc[oo] = fz;
    #pragma unroll 1
    for (int st = 0; st < 16; ++st) {
        const int sn = eta * 16 + st;
        h4 bf = {(_Float16)0.f, (_Float16)0.f, (_Float16)0.f, (_Float16)0.f};
        if (hh < 2) bf = *(const h4*)(xrow + sn * 8);
        const _Float16* wr = wl + sn * WROW + c * DI + ioff;
        #pragma unroll
        for (int oo = 0; oo < O_; ++oo) {
            h4 af = {(_Float16)0.f, (_Float16)0.f, (_Float16)0.f, (_Float16)0.f};
            if (hh < 2) af = *(const h4*)(wr + oo * (DO_ * DI));
            acc[oo] = __builtin_amdgcn_mfma_f32_16x16x16f16(af, bf, acc[oo], 0, 0, 0);
        }
    }
    epi(0.1f);
    gbar_arrive(cnt, flag, 1); gbar_wait(flag, 1);
    if (bid < B_) reduceF(0);
    gbar_arrive(cnt, flag, 2); gbar_wait(flag, 2);
    loadvv();

    // ---- round 1 ----
    #pragma unroll
    for (int oo = 0; oo < O_; ++oo) acc[oo] = fz;
    #pragma unroll 1
    for (int st = 0; st < 16; ++st) step1(eta * 16 + st);
    epi(1.0f);
    gbar_arrive(cnt, flag, 3); gbar_wait(flag, 3);
    if (bid < B_) reduceF(1);
    gbar_arrive(cnt, flag, 4); gbar_wait(flag, 4);
    loadvv();

    // ---- round 2 ----
    #pragma unroll
    for (int oo = 0; oo < O_; ++oo) acc[oo] = fz;
    #pragma unroll 1
    for (int st = 0; st < 16; ++st) step1(eta * 16 + st);
    epi(1.0f);

    // final: everyone arrives; only reducer blocks wait and finish
    gbar_arrive(cnt, flag, 5);
    if (bid < B_) {
        gbar_wait(flag, 5);
        reduceF(2);
    }
}

// ================= fallback path (R16 proven, atomic accumulator) =========
template <int PHASE, int TAIL>
__global__ __launch_bounds__(256, 3)
void caps_pass(const float* __restrict__ Xf, const float* __restrict__ Wf,
               const u16* __restrict__ Vb, float* __restrict__ Sout,
               _Float16* __restrict__ Sh) {
    __shared__ _Float16 stage[2 * CHH];

    const int tid  = threadIdx.x;
    const int lane = tid & 63;
    const int c    = lane & 15;
    const int hh   = lane >> 4;
    const int tau  = __builtin_amdgcn_readfirstlane(tid >> 6);
    const int b    = tau * 16 + c;
    const int nb   = blockIdx.x * NCHUNK;
    const int a32  = (lane ^ 32) << 2;

    int off[5];
    #pragma unroll
    for (int k = 0; k < 5; ++k) off[k] = (tid + k * 256) * 2;

    float2 st[5];
    {
        const float* src = Wf + (size_t)nb * WROW;
        #pragma unroll
        for (int k = 0; k < 5; ++k) st[k] = *(const float2*)(src + off[k]);
        #pragma unroll
        for (int k = 0; k < 5; ++k)
            *(h2*)&stage[off[k]] = pkrtz(st[k].x, st[k].y);
    }

    f4 vv[O_];
    if (PHASE > 0) {
        const _Float16* vp = (const _Float16*)Vb + (size_t)b * OD + 4 * hh;
        #pragma unroll
        for (int oo = 0; oo < O_; ++oo) {
            const h4 hv = *(const h4*)(vp + oo * DO_);
            vv[oo][0] = (float)hv[0]; vv[oo][1] = (float)hv[1];
            vv[oo][2] = (float)hv[2]; vv[oo][3] = (float)hv[3];
        }
    }

    const f4 fz = {0.f, 0.f, 0.f, 0.f};
    f4 acc[O_];
    #pragma unroll
    for (int oo = 0; oo < O_; ++oo) acc[oo] = fz;

    const int ioff = (hh < 2) ? 4 * hh : 0;
    const float* xb = Xf + ((size_t)b * N_ + nb) * DI + ioff;
    float4 xcur = *(const float4*)xb;

    __syncthreads();

    #pragma unroll 1
    for (int ch = 0; ch < NCHK; ++ch) {
        if (ch < NCHK - 1) {
            const float* src = Wf + (size_t)(nb + (ch + 1) * CHN) * WROW;
            #pragma unroll
            for (int k = 0; k < 5; ++k) st[k] = *(const float2*)(src + off[k]);
        }
        const _Float16* wb = stage + (ch & 1) * CHH;

        #pragma unroll
        for (int kk = 0; kk < CHN; ++kk) {
            const int s = ch * CHN + kk;
            float4 xnext = xcur;
            if (s < NCHUNK - 1)
                xnext = *(const float4*)(xb + (size_t)(s + 1) * DI);

            h4 bf = {(_Float16)0.f, (_Float16)0.f, (_Float16)0.f, (_Float16)0.f};
            if (hh < 2) {
                const h2 lo = pkrtz(xcur.x, xcur.y);
                const h2 hi = pkrtz(xcur.z, xcur.w);
                bf[0] = lo[0]; bf[1] = lo[1]; bf[2] = hi[0]; bf[3] = hi[1];
            }
            xcur = xnext;

            const _Float16* wr = wb + kk * WROW + c * DI + ioff;
            f4 u[O_];
            #pragma unroll
            for (int oo = 0; oo < O_; ++oo) {
                h4 af = {(_Float16)0.f, (_Float16)0.f, (_Float16)0.f, (_Float16)0.f};
                if (hh < 2) af = *(const h4*)(wr + oo * (DO_ * DI));
                if (PHASE == 0) {
                    acc[oo] = __builtin_amdgcn_mfma_f32_16x16x16f16(af, bf, acc[oo], 0, 0, 0);
                } else {
                    u[oo] = __builtin_amdgcn_mfma_f32_16x16x16f16(af, bf, fz, 0, 0, 0);
                }
            }

            if (PHASE > 0) {
                float tex[O_];
                #pragma unroll
                for (int q = 0; q < 5; ++q) {
                    const int o0 = 2 * q, o1 = 2 * q + 1;
                    const float p0 = u[o0][0]*vv[o0][0] + u[o0][1]*vv[o0][1]
                                   + u[o0][2]*vv[o0][2] + u[o0][3]*vv[o0][3];
                    const float p1 = u[o1][0]*vv[o1][0] + u[o1][1]*vv[o1][1]
                                   + u[o1][2]*vv[o1][2] + u[o1][3]*vv[o1][3];
                    const h2 pk = hsum4(pkrtz(p0, p1), a32);
                    tex[o0] = __expf((float)pk[0]);
                    tex[o1] = __expf((float)pk[1]);
                }
                const float den = (((tex[0] + tex[1]) + (tex[2] + tex[3]))
                                 + ((tex[4] + tex[5]) + (tex[6] + tex[7])))
                                 + (tex[8] + tex[9]);
                const float rinv = 1.0f / den;
                #pragma unroll
                for (int oo = 0; oo < O_; ++oo) {
                    const float co = tex[oo] * rinv;
                    acc[oo][0] = fmaf(co, u[oo][0], acc[oo][0]);
                    acc[oo][1] = fmaf(co, u[oo][1], acc[oo][1]);
                    acc[oo][2] = fmaf(co, u[oo][2], acc[oo][2]);
                    acc[oo][3] = fmaf(co, u[oo][3], acc[oo][3]);
                }
            }
        }

        if (ch < NCHK - 1) {
            _Float16* dst = stage + ((ch + 1) & 1) * CHH;
            #pragma unroll
            for (int k = 0; k < 5; ++k)
                *(h2*)&dst[off[k]] = pkrtz(st[k].x, st[k].y);
        }
        __syncthreads();
    }

    const float sc = (PHASE == 0) ? 0.1f : 1.0f;
    {
        float* Sg = Sout + (size_t)b * OD;
        #pragma unroll
        for (int oo = 0; oo < O_; ++oo) {
            atomicAdd(&Sg[oo * DO_ + 4 * hh + 0], sc * acc[oo][0]);
            atomicAdd(&Sg[oo * DO_ + 4 * hh + 1], sc * acc[oo][1]);
            atomicAdd(&Sg[oo * DO_ + 4 * hh + 2], sc * acc[oo][2]);
            atomicAdd(&Sg[oo * DO_ + 4 * hh + 3], sc * acc[oo][3]);
        }
    }
    (void)Sh;
}

template <int PHASE>
__global__ __launch_bounds__(1024)
void caps_finalize(float* __restrict__ S, float* __restrict__ V0f,
                   u16* __restrict__ Vb, float* __restrict__ out) {
    const int tid = threadIdx.x;
    const int b = tid >> 4, d = tid & 15;
    float sv[O_];
    float norm = 0.0f;
    #pragma unroll
    for (int o = 0; o < O_; ++o) {
        sv[o] = S[b * OD + o * DO_ + d];
        norm = fmaf(sv[o], sv[o], norm);
    }
    const float scale = norm / (1.0f + norm) * rsqrtf(norm + 1e-9f);
    #pragma unroll
    for (int o = 0; o < O_; ++o) {
        const int idx = b * OD + o * DO_ + d;
        const float v = scale * sv[o];
        if (PHASE == 0) {
            V0f[idx] = v;
            _Float16 hcv = (_Float16)v;
            Vb[idx] = __builtin_bit_cast(u16, hcv);
            S[idx] = 0.0f;
        } else if (PHASE == 1) {
            _Float16 hcv = (_Float16)(V0f[idx] + v);
            Vb[idx] = __builtin_bit_cast(u16, hcv);
            S[idx] = 0.0f;
        } else {
            out[idx] = v;
        }
    }
}

extern "C" void kernel_launch(void* const* d_in, const int* in_sizes, int n_in,
                              void* d_out, int out_size, void* d_ws, size_t ws_size,
                              hipStream_t stream) {
    const float* Xf = (const float*)d_in[0];   // x: [64, 8192, 8] fp32
    const float* Wf = (const float*)d_in[1];   // W: [1, 8192, 10, 16, 8] fp32
    float* out = (float*)d_out;

    const size_t velems = (size_t)B_ * OD;                 // 10240
    float* V0f = (float*)d_ws;                             // 40960 B
    u16* Vb = (u16*)(V0f + velems);                        // 20480 B -> ends 61440
    u32* bar = (u32*)((char*)d_ws + 61440);                // 256 B: cnt + flag lines
    const size_t pbase = 61696;
    const size_t need = pbase + (size_t)NB * velems * 2;   // ~5.3 MB

    if (ws_size >= need) {
        _Float16* P = (_Float16*)((char*)d_ws + pbase);
        (void)hipMemsetAsync(bar, 0, 256, stream);
        caps_fused<<<dim3(NB), dim3(512), 0, stream>>>(Xf, Wf, bar, V0f, Vb, P, out);
    } else {
        // fallback: global atomic accumulator (R16 proven path)
        float* S = (float*)((char*)d_ws + pbase);
        const dim3 grid(N_ / NCHUNK), blk(256), one(1), fblk(1024);
        (void)hipMemsetAsync(S, 0, velems * sizeof(float), stream);
        caps_pass<0, 2><<<grid, blk, 0, stream>>>(Xf, Wf, nullptr, S, nullptr);
        caps_finalize<0><<<one, fblk, 0, stream>>>(S, V0f, Vb, nullptr);
        caps_pass<1, 2><<<grid, blk, 0, stream>>>(Xf, Wf, Vb, S, nullptr);
        caps_finalize<1><<<one, fblk, 0, stream>>>(S, V0f, Vb, nullptr);
        caps_pass<1, 2><<<grid, blk, 0, stream>>>(Xf, Wf, Vb, S, nullptr);
        caps_finalize<2><<<one, fblk, 0, stream>>>(S, nullptr, nullptr, out);
    }
}

// Round 8
// 203.921 us; speedup vs baseline: 3.8340x; 2.6237x over previous
//
#include <hip/hip_runtime.h>

typedef unsigned int u32;
typedef unsigned short u16;
typedef _Float16 h2 __attribute__((ext_vector_type(2)));
typedef _Float16 h4 __attribute__((ext_vector_type(4)));
typedef float f4 __attribute__((ext_vector_type(4)));

#define B_ 64
#define N_ 8192
#define DI 8
#define O_ 10
#define DO_ 16
#define OD 160          // O_*DO_
#define NB 256          // fused grid: 1 block/CU, all co-resident (LDS-forced)
#define NCH 32          // n per block (fused): 256*32 = 8192
#define WROW (OD * DI)  // 1280 elems per n
#define WLN (NCH * WROW)// 40960 f16 = 81920 B
#define XROW 264        // padded x row per b (f16)
#define CSTR 164        // combine row stride (floats), proven R13

// ---- fallback (R16 proven) params ----
#define NCHUNK 8
#define CHN 2
#define NCHK (NCHUNK / CHN)
#define CHH (CHN * WROW)

// cvt_pkrtz returns __fp16-vec2; bit_cast to our _Float16-vec2 (same bits).
static __device__ __forceinline__ h2 pkrtz(float a, float b) {
    return __builtin_bit_cast(h2, __builtin_amdgcn_cvt_pkrtz(a, b));
}

// Packed-f16 sum across the four 16-lane rows, replicated to all lanes --
// PROVEN R13 chain (ds_swizzle xor^16 + ds_bpermute xor^32). permlane swaps
// are NOT equivalent (R14/R15 evidence); do not substitute.
static __device__ __forceinline__ h2 hsum4(h2 v, int a32) {
    int pi = __builtin_bit_cast(int, v);
    h2 pk = v + __builtin_bit_cast(h2, __builtin_amdgcn_ds_swizzle(pi, 0x401F));
    pi = __builtin_bit_cast(int, pk);
    pk = pk + __builtin_bit_cast(h2, __builtin_amdgcn_ds_bpermute(a32, pi));
    return pk;
}

// R19 barrier: R18 still burned ~85us/barrier -- __threadfence() was executed
// by ALL 512 threads on BOTH sides (8 waves x 256 blocks x 2 x 5 = 20K
// cache-wide wbL2/inv scans). Fences are cache-wide and issuer-agnostic:
// ONE per block suffices.
//   arrive: __syncthreads (intra-block order) -> thread0 fetch_add RELEASE
//           (single L2 writeback publishes the whole block's writes);
//           last arriver stores flag RELEASE.
//   wait  : thread0 RELAXED poll (no cache ops) -> ONE ACQUIRE load
//           (single L1/L2 invalidate; L1 is per-CU, shared by the block)
//           -> __syncthreads releases the block.
static __device__ __forceinline__ void gbar_arrive(u32* cnt, u32* flag, u32 k) {
    __syncthreads();
    if (threadIdx.x == 0) {
        const u32 old = __hip_atomic_fetch_add(cnt, 1u, __ATOMIC_RELEASE,
                                               __HIP_MEMORY_SCOPE_AGENT);
        if (old == k * NB - 1)
            __hip_atomic_store(flag, k, __ATOMIC_RELEASE, __HIP_MEMORY_SCOPE_AGENT);
    }
}
static __device__ __forceinline__ void gbar_wait(u32* flag, u32 k) {
    if (threadIdx.x == 0) {
        while (__hip_atomic_load(flag, __ATOMIC_RELAXED, __HIP_MEMORY_SCOPE_AGENT) < k)
            __builtin_amdgcn_s_sleep(8);
        (void)__hip_atomic_load(flag, __ATOMIC_ACQUIRE, __HIP_MEMORY_SCOPE_AGENT);
    }
    __syncthreads();
}

// R19 = R18 fused persistent kernel (traffic proven: 54 MB total vs 585 MB
// for 3 passes) with once-per-block fencing. W (80 KB) + x (33 KB) staged to
// LDS as f16 once; 3 routing rounds from LDS; cross-block reduce via fp16
// partials; blocks 0..63 reduce+squash in-kernel.
__global__ __launch_bounds__(512, 2)
void caps_fused(const float* __restrict__ Xf, const float* __restrict__ Wf,
                u32* bar, float* __restrict__ V0f, u16* __restrict__ Vb,
                _Float16* __restrict__ P, float* __restrict__ out) {
    __shared__ _Float16 wl[WLN];            // 81920 B
    __shared__ _Float16 xl[B_ * XROW];      // 33792 B
    __shared__ float cmb[B_ * CSTR];        // 41984 B (combine + reduce scratch)

    const int tid  = threadIdx.x;
    const int lane = tid & 63;
    const int c    = lane & 15;
    const int hh   = lane >> 4;
    const int w    = __builtin_amdgcn_readfirstlane(tid >> 6);
    const int tau  = w & 3, eta = w >> 2;
    const int b    = tau * 16 + c;
    const int bid  = blockIdx.x;
    const int nb   = bid * NCH;
    const int a32  = (lane ^ 32) << 2;
    const int ioff = (hh < 2) ? 4 * hh : 0;

    u32* cnt  = bar;
    u32* flag = bar + 32;    // separate 128-B cache line

    // ---- stage W + x (issue all loads first, then convert+write) ----
    {
        const float* src = Wf + (size_t)nb * WROW;
        float4 wv[20];
        #pragma unroll
        for (int k = 0; k < 20; ++k) wv[k] = *(const float4*)(src + (tid + k * 512) * 4);
        const float* xs = Xf + ((size_t)(tid >> 3) * N_ + nb) * DI;
        float4 xv[8];
        #pragma unroll
        for (int k = 0; k < 8; ++k) xv[k] = *(const float4*)(xs + ((tid & 7) + k * 8) * 4);
        #pragma unroll
        for (int k = 0; k < 20; ++k) {
            h2 lo = pkrtz(wv[k].x, wv[k].y), hi = pkrtz(wv[k].z, wv[k].w);
            h4 hv; hv[0] = lo[0]; hv[1] = lo[1]; hv[2] = hi[0]; hv[3] = hi[1];
            *(h4*)&wl[(tid + k * 512) * 4] = hv;
        }
        #pragma unroll
        for (int k = 0; k < 8; ++k) {
            const int pos = ((tid & 7) + k * 8) * 4;
            h2 lo = pkrtz(xv[k].x, xv[k].y), hi = pkrtz(xv[k].z, xv[k].w);
            h4 hv; hv[0] = lo[0]; hv[1] = lo[1]; hv[2] = hi[0]; hv[3] = hi[1];
            *(h4*)&xl[(tid >> 3) * XROW + pos] = hv;
        }
    }
    __syncthreads();

    const f4 fz = {0.f, 0.f, 0.f, 0.f};
    f4 acc[O_], vv[O_];
    const _Float16* xrow = xl + b * XROW + ioff;

    auto loadvv = [&]() {
        const _Float16* vp = (const _Float16*)Vb + (size_t)b * OD + 4 * hh;
        #pragma unroll
        for (int oo = 0; oo < O_; ++oo) {
            const h4 hv = *(const h4*)(vp + oo * DO_);
            vv[oo][0] = (float)hv[0]; vv[oo][1] = (float)hv[1];
            vv[oo][2] = (float)hv[2]; vv[oo][3] = (float)hv[3];
        }
    };

    auto step1 = [&](int sn) {
        h4 bf = {(_Float16)0.f, (_Float16)0.f, (_Float16)0.f, (_Float16)0.f};
        if (hh < 2) bf = *(const h4*)(xrow + sn * 8);
        const _Float16* wr = wl + sn * WROW + c * DI + ioff;
        f4 u[O_];
        #pragma unroll
        for (int oo = 0; oo < O_; ++oo) {
            h4 af = {(_Float16)0.f, (_Float16)0.f, (_Float16)0.f, (_Float16)0.f};
            if (hh < 2) af = *(const h4*)(wr + oo * (DO_ * DI));
            u[oo] = __builtin_amdgcn_mfma_f32_16x16x16f16(af, bf, fz, 0, 0, 0);
        }
        float tex[O_];
        #pragma unroll
        for (int q = 0; q < 5; ++q) {
            const int o0 = 2 * q, o1 = 2 * q + 1;
            const float p0 = u[o0][0]*vv[o0][0] + u[o0][1]*vv[o0][1]
                           + u[o0][2]*vv[o0][2] + u[o0][3]*vv[o0][3];
            const float p1 = u[o1][0]*vv[o1][0] + u[o1][1]*vv[o1][1]
                           + u[o1][2]*vv[o1][2] + u[o1][3]*vv[o1][3];
            const h2 pk = hsum4(pkrtz(p0, p1), a32);
            tex[o0] = __expf((float)pk[0]);
            tex[o1] = __expf((float)pk[1]);
        }
        const float den = (((tex[0] + tex[1]) + (tex[2] + tex[3]))
                         + ((tex[4] + tex[5]) + (tex[6] + tex[7])))
                         + (tex[8] + tex[9]);
        const float rinv = 1.0f / den;
        #pragma unroll
        for (int oo = 0; oo < O_; ++oo) {
            const float co = tex[oo] * rinv;
            acc[oo][0] = fmaf(co, u[oo][0], acc[oo][0]);
            acc[oo][1] = fmaf(co, u[oo][1], acc[oo][1]);
            acc[oo][2] = fmaf(co, u[oo][2], acc[oo][2]);
            acc[oo][3] = fmaf(co, u[oo][3], acc[oo][3]);
        }
    };

    auto epi = [&](float sc) {
        if (eta == 1) {
            #pragma unroll
            for (int oo = 0; oo < O_; ++oo)
                *(f4*)&cmb[b * CSTR + oo * DO_ + 4 * hh] = acc[oo];
        }
        __syncthreads();
        if (eta == 0) {
            _Float16* my = P + (size_t)bid * (B_ * OD) + (size_t)b * OD;
            #pragma unroll
            for (int oo = 0; oo < O_; ++oo) {
                const f4 t = acc[oo] + *(const f4*)&cmb[b * CSTR + oo * DO_ + 4 * hh];
                h4 hq;
                hq[0] = (_Float16)(sc * t[0]); hq[1] = (_Float16)(sc * t[1]);
                hq[2] = (_Float16)(sc * t[2]); hq[3] = (_Float16)(sc * t[3]);
                *(h4*)(my + oo * DO_ + 4 * hh) = hq;
            }
        }
    };

    auto reduceF = [&](int r) {
        float* sg = cmb;
        float* ss = cmb + 512;
        float* sca = cmb + 704;
        if (tid < 480) {
            const int g = tid / 160, od = tid - g * 160;
            float a2 = 0.0f;
            const _Float16* p0 = P + (size_t)bid * OD + od;
            #pragma unroll 8
            for (int p = g; p < NB; p += 3)
                a2 += (float)p0[(size_t)p * (B_ * OD)];
            sg[g * 160 + od] = a2;
        }
        __syncthreads();
        if (tid < 160) ss[tid] = sg[tid] + sg[160 + tid] + sg[320 + tid];
        __syncthreads();
        if (tid < 16) {
            float nrm = 0.0f;
            #pragma unroll
            for (int o = 0; o < O_; ++o) { const float x = ss[o * DO_ + tid]; nrm = fmaf(x, x, nrm); }
            sca[tid] = nrm / (1.0f + nrm) * rsqrtf(nrm + 1e-9f);
        }
        __syncthreads();
        if (tid < 160) {
            const float v = ss[tid] * sca[tid & 15];
            const int idx = bid * OD + tid;
            if (r == 0) {
                V0f[idx] = v;
                _Float16 hcv = (_Float16)v;
                Vb[idx] = __builtin_bit_cast(u16, hcv);
            } else if (r == 1) {
                _Float16 hcv = (_Float16)(V0f[idx] + v);
                Vb[idx] = __builtin_bit_cast(u16, hcv);
            } else {
                out[idx] = v;
            }
        }
        __syncthreads();
    };

    // ---- round 0: uniform c = 0.1, chain through MFMA C ----
    #pragma unroll
    for (int oo = 0; oo < O_; ++oo) acc[oo] = fz;
    #pragma unroll 1
    for (int st = 0; st < 16; ++st) {
        const int sn = eta * 16 + st;
        h4 bf = {(_Float16)0.f, (_Float16)0.f, (_Float16)0.f, (_Float16)0.f};
        if (hh < 2) bf = *(const h4*)(xrow + sn * 8);
        const _Float16* wr = wl + sn * WROW + c * DI + ioff;
        #pragma unroll
        for (int oo = 0; oo < O_; ++oo) {
            h4 af = {(_Float16)0.f, (_Float16)0.f, (_Float16)0.f, (_Float16)0.f};
            if (hh < 2) af = *(const h4*)(wr + oo * (DO_ * DI));
            acc[oo] = __builtin_amdgcn_mfma_f32_16x16x16f16(af, bf, acc[oo], 0, 0, 0);
        }
    }
    epi(0.1f);
    gbar_arrive(cnt, flag, 1); gbar_wait(flag, 1);
    if (bid < B_) reduceF(0);
    gbar_arrive(cnt, flag, 2); gbar_wait(flag, 2);
    loadvv();

    // ---- round 1 ----
    #pragma unroll
    for (int oo = 0; oo < O_; ++oo) acc[oo] = fz;
    #pragma unroll 1
    for (int st = 0; st < 16; ++st) step1(eta * 16 + st);
    epi(1.0f);
    gbar_arrive(cnt, flag, 3); gbar_wait(flag, 3);
    if (bid < B_) reduceF(1);
    gbar_arrive(cnt, flag, 4); gbar_wait(flag, 4);
    loadvv();

    // ---- round 2 ----
    #pragma unroll
    for (int oo = 0; oo < O_; ++oo) acc[oo] = fz;
    #pragma unroll 1
    for (int st = 0; st < 16; ++st) step1(eta * 16 + st);
    epi(1.0f);

    // final: everyone arrives; only reducer blocks wait and finish
    gbar_arrive(cnt, flag, 5);
    if (bid < B_) {
        gbar_wait(flag, 5);
        reduceF(2);
    }
}

// ================= fallback path (R16 proven, atomic accumulator) =========
template <int PHASE, int TAIL>
__global__ __launch_bounds__(256, 3)
void caps_pass(const float* __restrict__ Xf, const float* __restrict__ Wf,
               const u16* __restrict__ Vb, float* __restrict__ Sout,
               _Float16* __restrict__ Sh) {
    __shared__ _Float16 stage[2 * CHH];

    const int tid  = threadIdx.x;
    const int lane = tid & 63;
    const int c    = lane & 15;
    const int hh   = lane >> 4;
    const int tau  = __builtin_amdgcn_readfirstlane(tid >> 6);
    const int b    = tau * 16 + c;
    const int nb   = blockIdx.x * NCHUNK;
    const int a32  = (lane ^ 32) << 2;

    int off[5];
    #pragma unroll
    for (int k = 0; k < 5; ++k) off[k] = (tid + k * 256) * 2;

    float2 st[5];
    {
        const float* src = Wf + (size_t)nb * WROW;
        #pragma unroll
        for (int k = 0; k < 5; ++k) st[k] = *(const float2*)(src + off[k]);
        #pragma unroll
        for (int k = 0; k < 5; ++k)
            *(h2*)&stage[off[k]] = pkrtz(st[k].x, st[k].y);
    }

    f4 vv[O_];
    if (PHASE > 0) {
        const _Float16* vp = (const _Float16*)Vb + (size_t)b * OD + 4 * hh;
        #pragma unroll
        for (int oo = 0; oo < O_; ++oo) {
            const h4 hv = *(const h4*)(vp + oo * DO_);
            vv[oo][0] = (float)hv[0]; vv[oo][1] = (float)hv[1];
            vv[oo][2] = (float)hv[2]; vv[oo][3] = (float)hv[3];
        }
    }

    const f4 fz = {0.f, 0.f, 0.f, 0.f};
    f4 acc[O_];
    #pragma unroll
    for (int oo = 0; oo < O_; ++oo) acc[oo] = fz;

    const int ioff = (hh < 2) ? 4 * hh : 0;
    const float* xb = Xf + ((size_t)b * N_ + nb) * DI + ioff;
    float4 xcur = *(const float4*)xb;

    __syncthreads();

    #pragma unroll 1
    for (int ch = 0; ch < NCHK; ++ch) {
        if (ch < NCHK - 1) {
            const float* src = Wf + (size_t)(nb + (ch + 1) * CHN) * WROW;
            #pragma unroll
            for (int k = 0; k < 5; ++k) st[k] = *(const float2*)(src + off[k]);
        }
        const _Float16* wb = stage + (ch & 1) * CHH;

        #pragma unroll
        for (int kk = 0; kk < CHN; ++kk) {
            const int s = ch * CHN + kk;
            float4 xnext = xcur;
            if (s < NCHUNK - 1)
                xnext = *(const float4*)(xb + (size_t)(s + 1) * DI);

            h4 bf = {(_Float16)0.f, (_Float16)0.f, (_Float16)0.f, (_Float16)0.f};
            if (hh < 2) {
                const h2 lo = pkrtz(xcur.x, xcur.y);
                const h2 hi = pkrtz(xcur.z, xcur.w);
                bf[0] = lo[0]; bf[1] = lo[1]; bf[2] = hi[0]; bf[3] = hi[1];
            }
            xcur = xnext;

            const _Float16* wr = wb + kk * WROW + c * DI + ioff;
            f4 u[O_];
            #pragma unroll
            for (int oo = 0; oo < O_; ++oo) {
                h4 af = {(_Float16)0.f, (_Float16)0.f, (_Float16)0.f, (_Float16)0.f};
                if (hh < 2) af = *(const h4*)(wr + oo * (DO_ * DI));
                if (PHASE == 0) {
                    acc[oo] = __builtin_amdgcn_mfma_f32_16x16x16f16(af, bf, acc[oo], 0, 0, 0);
                } else {
                    u[oo] = __builtin_amdgcn_mfma_f32_16x16x16f16(af, bf, fz, 0, 0, 0);
                }
            }

            if (PHASE > 0) {
                float tex[O_];
                #pragma unroll
                for (int q = 0; q < 5; ++q) {
                    const int o0 = 2 * q, o1 = 2 * q + 1;
                    const float p0 = u[o0][0]*vv[o0][0] + u[o0][1]*vv[o0][1]
                                   + u[o0][2]*vv[o0][2] + u[o0][3]*vv[o0][3];
                    const float p1 = u[o1][0]*vv[o1][0] + u[o1][1]*vv[o1][1]
                                   + u[o1][2]*vv[o1][2] + u[o1][3]*vv[o1][3];
                    const h2 pk = hsum4(pkrtz(p0, p1), a32);
                    tex[o0] = __expf((float)pk[0]);
                    tex[o1] = __expf((float)pk[1]);
                }
                const float den = (((tex[0] + tex[1]) + (tex[2] + tex[3]))
                                 + ((tex[4] + tex[5]) + (tex[6] + tex[7])))
                                 + (tex[8] + tex[9]);
                const float rinv = 1.0f / den;
                #pragma unroll
                for (int oo = 0; oo < O_; ++oo) {
                    const float co = tex[oo] * rinv;
                    acc[oo][0] = fmaf(co, u[oo][0], acc[oo][0]);
                    acc[oo][1] = fmaf(co, u[oo][1], acc[oo][1]);
                    acc[oo][2] = fmaf(co, u[oo][2], acc[oo][2]);
                    acc[oo][3] = fmaf(co, u[oo][3], acc[oo][3]);
                }
            }
        }

        if (ch < NCHK - 1) {
            _Float16* dst = stage + ((ch + 1) & 1) * CHH;
            #pragma unroll
            for (int k = 0; k < 5; ++k)
                *(h2*)&dst[off[k]] = pkrtz(st[k].x, st[k].y);
        }
        __syncthreads();
    }

    const float sc = (PHASE == 0) ? 0.1f : 1.0f;
    {
        float* Sg = Sout + (size_t)b * OD;
        #pragma unroll
        for (int oo = 0; oo < O_; ++oo) {
            atomicAdd(&Sg[oo * DO_ + 4 * hh + 0], sc * acc[oo][0]);
            atomicAdd(&Sg[oo * DO_ + 4 * hh + 1], sc * acc[oo][1]);
            atomicAdd(&Sg[oo * DO_ + 4 * hh + 2], sc * acc[oo][2]);
            atomicAdd(&Sg[oo * DO_ + 4 * hh + 3], sc * acc[oo][3]);
        }
    }
    (void)Sh;
}

template <int PHASE>
__global__ __launch_bounds__(1024)
void caps_finalize(float* __restrict__ S, float* __restrict__ V0f,
                   u16* __restrict__ Vb, float* __restrict__ out) {
    const int tid = threadIdx.x;
    const int b = tid >> 4, d = tid & 15;
    float sv[O_];
    float norm = 0.0f;
    #pragma unroll
    for (int o = 0; o < O_; ++o) {
        sv[o] = S[b * OD + o * DO_ + d];
        norm = fmaf(sv[o], sv[o], norm);
    }
    const float scale = norm / (1.0f + norm) * rsqrtf(norm + 1e-9f);
    #pragma unroll
    for (int o = 0; o < O_; ++o) {
        const int idx = b * OD + o * DO_ + d;
        const float v = scale * sv[o];
        if (PHASE == 0) {
            V0f[idx] = v;
            _Float16 hcv = (_Float16)v;
            Vb[idx] = __builtin_bit_cast(u16, hcv);
            S[idx] = 0.0f;
        } else if (PHASE == 1) {
            _Float16 hcv = (_Float16)(V0f[idx] + v);
            Vb[idx] = __builtin_bit_cast(u16, hcv);
            S[idx] = 0.0f;
        } else {
            out[idx] = v;
        }
    }
}

extern "C" void kernel_launch(void* const* d_in, const int* in_sizes, int n_in,
                              void* d_out, int out_size, void* d_ws, size_t ws_size,
                              hipStream_t stream) {
    const float* Xf = (const float*)d_in[0];   // x: [64, 8192, 8] fp32
    const float* Wf = (const float*)d_in[1];   // W: [1, 8192, 10, 16, 8] fp32
    float* out = (float*)d_out;

    const size_t velems = (size_t)B_ * OD;                 // 10240
    float* V0f = (float*)d_ws;                             // 40960 B
    u16* Vb = (u16*)(V0f + velems);                        // 20480 B -> ends 61440
    u32* bar = (u32*)((char*)d_ws + 61440);                // 256 B: cnt + flag lines
    const size_t pbase = 61696;
    const size_t need = pbase + (size_t)NB * velems * 2;   // ~5.3 MB

    if (ws_size >= need) {
        _Float16* P = (_Float16*)((char*)d_ws + pbase);
        (void)hipMemsetAsync(bar, 0, 256, stream);
        caps_fused<<<dim3(NB), dim3(512), 0, stream>>>(Xf, Wf, bar, V0f, Vb, P, out);
    } else {
        // fallback: global atomic accumulator (R16 proven path)
        float* S = (float*)((char*)d_ws + pbase);
        const dim3 grid(N_ / NCHUNK), blk(256), one(1), fblk(1024);
        (void)hipMemsetAsync(S, 0, velems * sizeof(float), stream);
        caps_pass<0, 2><<<grid, blk, 0, stream>>>(Xf, Wf, nullptr, S, nullptr);
        caps_finalize<0><<<one, fblk, 0, stream>>>(S, V0f, Vb, nullptr);
        caps_pass<1, 2><<<grid, blk, 0, stream>>>(Xf, Wf, Vb, S, nullptr);
        caps_finalize<1><<<one, fblk, 0, stream>>>(S, V0f, Vb, nullptr);
        caps_pass<1, 2><<<grid, blk, 0, stream>>>(Xf, Wf, Vb, S, nullptr);
        caps_finalize<2><<<one, fblk, 0, stream>>>(S, nullptr, nullptr, out);
    }
}